// Round 1
// baseline (380.110 us; speedup 1.0000x reference)
//
#include <hip/hip_runtime.h>
#include <stdint.h>

typedef float f32x4 __attribute__((ext_vector_type(4)));
typedef short s16x8 __attribute__((ext_vector_type(8)));
typedef short s16x4 __attribute__((ext_vector_type(4)));

static constexpr int NROWS = 16384;

__device__ __forceinline__ unsigned short f2bf(float f) {
    uint32_t u = __float_as_uint(f);
    u += 0x7FFFu + ((u >> 16) & 1u);   // round-to-nearest-even
    return (unsigned short)(u >> 16);
}

__device__ __forceinline__ float wave_sum(float v) {
#pragma unroll
    for (int m = 1; m < 64; m <<= 1) v += __shfl_xor(v, m);
    return v;
}

// ---------- normalize memory rows -> bf16 in ws ----------
template<int C>
__global__ __launch_bounds__(256) void prep_mem_kernel(const float* __restrict__ mp,
                                                       short* __restrict__ nmp) {
    const int wave = threadIdx.x >> 6;
    const int lane = threadIdx.x & 63;
    const int row = blockIdx.x * 4 + wave;            // 256 blocks x 4 rows = 1024
    const float4* src = (const float4*)(mp + (size_t)row * C);
    constexpr int IT = C / 256;
    float4 vals[IT];
    float ss = 0.f;
#pragma unroll
    for (int it = 0; it < IT; ++it) {
        float4 v = src[lane + it * 64];
        vals[it] = v;
        ss += v.x * v.x + v.y * v.y + v.z * v.z + v.w * v.w;
    }
    ss = wave_sum(ss);
    const float inv = 1.f / fmaxf(sqrtf(ss), 1e-12f);
    s16x4* dst = (s16x4*)(nmp + (size_t)row * C);
#pragma unroll
    for (int it = 0; it < IT; ++it) {
        float4 v = vals[it];
        s16x4 o;
        o[0] = (short)f2bf(v.x * inv);
        o[1] = (short)f2bf(v.y * inv);
        o[2] = (short)f2bf(v.z * inv);
        o[3] = (short)f2bf(v.w * inv);
        dst[lane + it * 64] = o;
    }
}

// ---------- fused: norm(feat) -> S=NF.NM^T -> softmax -> shrink -> L1 -> W, mf ----------
template<int C>
__global__ __launch_bounds__(512) void fused_kernel(const float* __restrict__ feat,
                                                    const float* __restrict__ memv,
                                                    const short* __restrict__ nm,
                                                    float* __restrict__ out_cat,
                                                    float* __restrict__ out_w) {
    constexpr int BM = 32;
    constexpr int CHUNKS = C / 8;                 // 16B bf16 chunks per row
    __shared__ short A_s[BM * C];                 // swizzled bf16 A tile
    __shared__ float red[8][BM];
    __shared__ float invn[BM];
    __shared__ int rowflag[BM];
    __shared__ int anyflag;

    const int tid = threadIdx.x;
    const int wave = tid >> 6;
    const int lane = tid & 63;
    const int g = lane >> 4;                      // MFMA lane group
    const int ml = lane & 15;
    const int row0 = blockIdx.x * BM;

    if (tid == 0) anyflag = 0;

    // ---- pass 1: row sumsq + copy f into concat output ----
    constexpr int IT = C / 256;
#pragma unroll
    for (int rr = 0; rr < 4; ++rr) {
        const int row = wave * 4 + rr;
        const float4* src = (const float4*)(feat + (size_t)(row0 + row) * C);
        float4* dst = (float4*)(out_cat + (size_t)(row0 + row) * (2 * C) + C);
        float ss = 0.f;
#pragma unroll
        for (int it = 0; it < IT; ++it) {
            float4 v = src[lane + it * 64];
            dst[lane + it * 64] = v;
            ss += v.x * v.x + v.y * v.y + v.z * v.z + v.w * v.w;
        }
        ss = wave_sum(ss);
        if (lane == 0) invn[row] = 1.f / fmaxf(sqrtf(ss), 1e-12f);
    }
    __syncthreads();

    // ---- pass 2: re-read (L2-hot), scale, bf16, XOR-swizzled LDS store ----
    constexpr int P2I = (4 * C) / 512;
#pragma unroll
    for (int x = 0; x < P2I; ++x) {
        const int ci = tid + x * 512;
        const int row = ci / CHUNKS;
        const int cc = ci & (CHUNKS - 1);
        const float4* src = (const float4*)(feat + (size_t)(row0 + row) * C + cc * 8);
        const float4 a = src[0];
        const float4 b = src[1];
        const float inv = invn[row];
        s16x8 p;
        p[0] = (short)f2bf(a.x * inv);
        p[1] = (short)f2bf(a.y * inv);
        p[2] = (short)f2bf(a.z * inv);
        p[3] = (short)f2bf(a.w * inv);
        p[4] = (short)f2bf(b.x * inv);
        p[5] = (short)f2bf(b.y * inv);
        p[6] = (short)f2bf(b.z * inv);
        p[7] = (short)f2bf(b.w * inv);
        const int swz = cc ^ (row & 7);           // bank-conflict swizzle (16B granule)
        *(s16x8*)&A_s[row * C + swz * 8] = p;
    }
    __syncthreads();

    // ---- K-loop: S tile [32 x 1024], wave owns cols [wave*128, +128) ----
    f32x4 acc[2][8];
#pragma unroll
    for (int rt = 0; rt < 2; ++rt)
#pragma unroll
        for (int t = 0; t < 8; ++t)
            acc[rt][t] = (f32x4){0.f, 0.f, 0.f, 0.f};

    const int swzm = ml & 7;
    for (int ks = 0; ks < C / 32; ++ks) {
        const int cbase = ks * 4 + g;
        const s16x8 a0 = *(const s16x8*)&A_s[ml * C + ((cbase ^ swzm) * 8)];
        const s16x8 a1 = *(const s16x8*)&A_s[(16 + ml) * C + ((cbase ^ swzm) * 8)];
        const short* nb = nm + (size_t)(wave * 128 + ml) * C + ks * 32 + 8 * g;
#pragma unroll
        for (int t = 0; t < 8; ++t) {
            const s16x8 b = *(const s16x8*)(nb + (size_t)t * 16 * C);
            acc[0][t] = __builtin_amdgcn_mfma_f32_16x16x32_bf16(a0, b, acc[0][t], 0, 0, 0);
            acc[1][t] = __builtin_amdgcn_mfma_f32_16x16x32_bf16(a1, b, acc[1][t], 0, 0, 0);
        }
    }

    // C/D layout: col = ml, row = 16*rt + 4*g + i   (i = reg idx)
    float Mx[2][4], Tt[2][4], IL[2][4];

    // ---- row max ----
#pragma unroll
    for (int rt = 0; rt < 2; ++rt)
#pragma unroll
        for (int i = 0; i < 4; ++i) {
            float m = acc[rt][0][i];
#pragma unroll
            for (int t = 1; t < 8; ++t) m = fmaxf(m, acc[rt][t][i]);
#pragma unroll
            for (int msk = 1; msk < 16; msk <<= 1) m = fmaxf(m, __shfl_xor(m, msk));
            if (ml == 0) red[wave][rt * 16 + g * 4 + i] = m;
        }
    __syncthreads();
#pragma unroll
    for (int rt = 0; rt < 2; ++rt)
#pragma unroll
        for (int i = 0; i < 4; ++i) {
            const int row = rt * 16 + g * 4 + i;
            float m = red[0][row];
#pragma unroll
            for (int ww = 1; ww < 8; ++ww) m = fmaxf(m, red[ww][row]);
            Mx[rt][i] = m;
        }
    __syncthreads();

    // ---- exp + row sum ----
#pragma unroll
    for (int rt = 0; rt < 2; ++rt)
#pragma unroll
        for (int i = 0; i < 4; ++i) {
            float s = 0.f;
#pragma unroll
            for (int t = 0; t < 8; ++t) {
                const float e = __expf(acc[rt][t][i] - Mx[rt][i]);
                acc[rt][t][i] = e;
                s += e;
            }
#pragma unroll
            for (int msk = 1; msk < 16; msk <<= 1) s += __shfl_xor(s, msk);
            if (ml == 0) red[wave][rt * 16 + g * 4 + i] = s;
        }
    __syncthreads();
#pragma unroll
    for (int rt = 0; rt < 2; ++rt)
#pragma unroll
        for (int i = 0; i < 4; ++i) {
            const int row = rt * 16 + g * 4 + i;
            float s = red[0][row];
#pragma unroll
            for (int ww = 1; ww < 8; ++ww) s += red[ww][row];
            Tt[rt][i] = s;
        }
    __syncthreads();

    // ---- softmax weight, hard-shrink, row L1 ----
#pragma unroll
    for (int rt = 0; rt < 2; ++rt)
#pragma unroll
        for (int i = 0; i < 4; ++i) {
            const float tinv = 1.f / Tt[rt][i];
            float l1 = 0.f;
#pragma unroll
            for (int t = 0; t < 8; ++t) {
                const float w = acc[rt][t][i] * tinv;
                const float d = w - 0.0025f;
                const float v = (d > 0.f) ? (d * w / (d + 1e-12f)) : 0.f;
                acc[rt][t][i] = v;
                l1 += v;
            }
#pragma unroll
            for (int msk = 1; msk < 16; msk <<= 1) l1 += __shfl_xor(l1, msk);
            if (ml == 0) red[wave][rt * 16 + g * 4 + i] = l1;
        }
    __syncthreads();
#pragma unroll
    for (int rt = 0; rt < 2; ++rt)
#pragma unroll
        for (int i = 0; i < 4; ++i) {
            const int row = rt * 16 + g * 4 + i;
            float l1 = red[0][row];
#pragma unroll
            for (int ww = 1; ww < 8; ++ww) l1 += red[ww][row];
            IL[rt][i] = 1.f / fmaxf(l1, 1e-12f);
            if (wave == 0 && ml == 0) {
                rowflag[row] = (l1 > 0.f) ? 1 : 0;
                if (l1 > 0.f) anyflag = 1;
            }
        }

    // ---- store W (always) ----
#pragma unroll
    for (int rt = 0; rt < 2; ++rt)
#pragma unroll
        for (int t = 0; t < 8; ++t) {
            const int col = wave * 128 + t * 16 + ml;
#pragma unroll
            for (int i = 0; i < 4; ++i) {
                out_w[(size_t)(row0 + rt * 16 + g * 4 + i) * 1024 + col] =
                    acc[rt][t][i] * IL[rt][i];
            }
        }
    __threadfence_block();
    __syncthreads();

    // ---- mf: zero fast-path (post-shrink all-dead) or sparse accumulate ----
    if (anyflag == 0) {
#pragma unroll
        for (int rr = 0; rr < 4; ++rr) {
            const int row = wave * 4 + rr;
            float4* dst = (float4*)(out_cat + (size_t)(row0 + row) * (2 * C));
            const float4 z = {0.f, 0.f, 0.f, 0.f};
#pragma unroll
            for (int it = 0; it < IT; ++it) dst[lane + it * 64] = z;
        }
    } else {
        constexpr int CC = C / 64;
#pragma unroll
        for (int rr = 0; rr < 4; ++rr) {
            const int row = wave * 4 + rr;
            float* dst = out_cat + (size_t)(row0 + row) * (2 * C);
            if (!rowflag[row]) {
#pragma unroll
                for (int cc = 0; cc < CC; ++cc) dst[cc * 64 + lane] = 0.f;
                continue;
            }
            float mfacc[CC];
#pragma unroll
            for (int cc = 0; cc < CC; ++cc) mfacc[cc] = 0.f;
            const float* wrow = out_w + (size_t)(row0 + row) * 1024;
            for (int jb = 0; jb < 1024; jb += 64) {
                const float wv = wrow[jb + lane];
                unsigned long long msk = __ballot(wv != 0.f);
                while (msk) {
                    const int j = __builtin_ctzll(msk);
                    msk &= msk - 1;
                    const float val = __shfl(wv, j);
                    const float* mrow = memv + (size_t)(jb + j) * C;
#pragma unroll
                    for (int cc = 0; cc < CC; ++cc)
                        mfacc[cc] += val * mrow[cc * 64 + lane];
                }
            }
#pragma unroll
            for (int cc = 0; cc < CC; ++cc) dst[cc * 64 + lane] = mfacc[cc];
        }
    }
}

extern "C" void kernel_launch(void* const* d_in, const int* in_sizes, int n_in,
                              void* d_out, int out_size, void* d_ws, size_t ws_size,
                              hipStream_t stream) {
    // setup_inputs dict order: feat0, mem0, feat1, mem1, feat2, mem2 — match by size for safety.
    const float* feat[3] = {nullptr, nullptr, nullptr};
    const float* memp[3] = {nullptr, nullptr, nullptr};
    for (int i = 0; i < n_in && i < 6; ++i) {
        const int s = in_sizes[i];
        const float* p = (const float*)d_in[i];
        if (s == 16384 * 256) feat[0] = p;
        else if (s == 16384 * 512) feat[1] = p;
        else if (s == 16384 * 1024) feat[2] = p;
        else if (s == 1024 * 256) memp[0] = p;
        else if (s == 1024 * 512) memp[1] = p;
        else if (s == 1024 * 1024) memp[2] = p;
    }
    float* out = (float*)d_out;
    short* nm0 = (short*)d_ws;
    short* nm1 = nm0 + 1024 * 256;
    short* nm2 = nm1 + 1024 * 512;

    // output layout (floats): out0 | out1 | out2 | w0 | w1 | w2
    const size_t O0 = 0;
    const size_t O1 = (size_t)16384 * 512;
    const size_t O2 = O1 + (size_t)16384 * 1024;
    const size_t W0 = O2 + (size_t)16384 * 2048;
    const size_t W1 = W0 + (size_t)16384 * 1024;
    const size_t W2 = W1 + (size_t)16384 * 1024;

    prep_mem_kernel<256><<<256, 256, 0, stream>>>(memp[0], nm0);
    prep_mem_kernel<512><<<256, 256, 0, stream>>>(memp[1], nm1);
    prep_mem_kernel<1024><<<256, 256, 0, stream>>>(memp[2], nm2);

    fused_kernel<256><<<512, 512, 0, stream>>>(feat[0], memp[0], nm0, out + O0, out + W0);
    fused_kernel<512><<<512, 512, 0, stream>>>(feat[1], memp[1], nm1, out + O1, out + W1);
    fused_kernel<1024><<<512, 512, 0, stream>>>(feat[2], memp[2], nm2, out + O2, out + W2);
}